// Round 1
// baseline (294.210 us; speedup 1.0000x reference)
//
#include <hip/hip_runtime.h>
#include <hip/hip_bf16.h>
#include <math.h>

#define B_SZ 16384
#define D_SZ 512
#define C_SZ 2000

typedef __bf16 bf16x8 __attribute__((ext_vector_type(8)));
typedef float f32x4 __attribute__((ext_vector_type(4)));
typedef unsigned short ushort8 __attribute__((ext_vector_type(8)));

__device__ __forceinline__ unsigned short f2bf(float f) {
  unsigned int u = __builtin_bit_cast(unsigned int, f);
  u += 0x7fffu + ((u >> 16) & 1u);
  return (unsigned short)(u >> 16);
}
__device__ __forceinline__ float bf2f(unsigned short h) {
  unsigned int u = ((unsigned int)h) << 16;
  return __builtin_bit_cast(float, u);
}

#define GLOBAL_AS __attribute__((address_space(1)))
#define LDS_AS __attribute__((address_space(3)))
__device__ __forceinline__ void async_copy16(const void* g, void* l) {
  __builtin_amdgcn_global_load_lds((const GLOBAL_AS unsigned int*)g,
                                   (LDS_AS unsigned int*)l, 16, 0, 0);
}

// ---------------- K0: cs/css precompute -> k1 = cs, k2 = 0.5*(cs^2 - css) ----
__global__ __launch_bounds__(256) void prep_cs(const float* __restrict__ cw,
                                               const float* __restrict__ prior,
                                               float* __restrict__ k1,
                                               float* __restrict__ k2) {
  __shared__ float ls[2][4][64];
  const int t = threadIdx.x;
  const int dl = t & 63, g = t >> 6;
  const int d = (blockIdx.x << 6) + dl;
  float s = 0.f, ss = 0.f;
  for (int c = g; c < C_SZ; c += 4) {
    float w = cw[(size_t)c * D_SZ + d] * prior[c];
    s += w; ss += w * w;
  }
  ls[0][g][dl] = s; ls[1][g][dl] = ss;
  __syncthreads();
  if (t < 64) {
    float cs  = ls[0][0][t] + ls[0][1][t] + ls[0][2][t] + ls[0][3][t];
    float css = ls[1][0][t] + ls[1][1][t] + ls[1][2][t] + ls[1][3][t];
    k1[(blockIdx.x << 6) + t] = cs;
    k2[(blockIdx.x << 6) + t] = 0.5f * (cs * cs - css);
  }
}

// ---------------- K0b: w1,w2 -> transposed bf16 [N][K] ----------------------
__global__ __launch_bounds__(256) void wt_conv(const float* __restrict__ w1,
                                               const float* __restrict__ w2,
                                               unsigned short* __restrict__ w1t,
                                               unsigned short* __restrict__ w2t) {
  int idx = blockIdx.x * 256 + threadIdx.x;  // 0..524287
  const float* src = w1; unsigned short* dst = w1t;
  int e = idx;
  if (idx >= 262144) { src = w2; dst = w2t; e = idx - 262144; }
  int k = e >> 9, n = e & 511;
  dst[(size_t)n * 512 + k] = f2bf(src[e]);
}

// ---------------- K1: gather + FM + reg partial -----------------------------
__device__ __forceinline__ float fme(float u, float i, float c, float a, float b2,
                                     float& reg) {
  float ucm = fmaf(u, a, b2);
  float s2 = u + i + c + ucm;
  float q2 = u * u + i * i + c * c + ucm * ucm;
  reg += u * u + i * i + c * c;
  return 0.5f * (s2 * s2 - q2);
}

__global__ __launch_bounds__(256) void gather_fm(
    const int* __restrict__ user, const int* __restrict__ item,
    const int* __restrict__ cate,
    const float* __restrict__ uw, const float* __restrict__ iw,
    const float* __restrict__ cw,
    const float* __restrict__ k1, const float* __restrict__ k2,
    unsigned short* __restrict__ fm, float* __restrict__ accs) {
  __shared__ float red[4];
  const int t = threadIdx.x, lane = t & 63, w = t >> 6;
  const int b = (blockIdx.x << 2) + w;
  const int d0 = lane << 3;
  const size_t uo = (size_t)user[b] * D_SZ + d0;
  const size_t io = (size_t)item[b] * D_SZ + d0;
  const size_t co = (size_t)cate[b] * D_SZ + d0;
  float4 u0 = *(const float4*)(uw + uo), u1 = *(const float4*)(uw + uo + 4);
  float4 i0 = *(const float4*)(iw + io), i1 = *(const float4*)(iw + io + 4);
  float4 c0 = *(const float4*)(cw + co), c1 = *(const float4*)(cw + co + 4);
  float4 a0 = *(const float4*)(k1 + d0), a1 = *(const float4*)(k1 + d0 + 4);
  float4 e0 = *(const float4*)(k2 + d0), e1 = *(const float4*)(k2 + d0 + 4);
  float regp = 0.f;
  ushort8 o;
  o[0] = f2bf(fme(u0.x, i0.x, c0.x, a0.x, e0.x, regp));
  o[1] = f2bf(fme(u0.y, i0.y, c0.y, a0.y, e0.y, regp));
  o[2] = f2bf(fme(u0.z, i0.z, c0.z, a0.z, e0.z, regp));
  o[3] = f2bf(fme(u0.w, i0.w, c0.w, a0.w, e0.w, regp));
  o[4] = f2bf(fme(u1.x, i1.x, c1.x, a1.x, e1.x, regp));
  o[5] = f2bf(fme(u1.y, i1.y, c1.y, a1.y, e1.y, regp));
  o[6] = f2bf(fme(u1.z, i1.z, c1.z, a1.z, e1.z, regp));
  o[7] = f2bf(fme(u1.w, i1.w, c1.w, a1.w, e1.w, regp));
  *(ushort8*)(fm + (size_t)b * D_SZ + d0) = o;
  #pragma unroll
  for (int off = 32; off; off >>= 1) regp += __shfl_down(regp, off);
  if (lane == 0) red[w] = regp;
  __syncthreads();
  if (t == 0) atomicAdd(&accs[1], red[0] + red[1] + red[2] + red[3]);
}

// ---------------- K2: bf16 GEMM (A[M,512] @ W[512,512]) + bias + relu -------
// Bt is W transposed to [N][K] row-major bf16. Output bf16 [M,512].
__global__ __launch_bounds__(256) void gemm_relu(
    const unsigned short* __restrict__ A, const unsigned short* __restrict__ Bt,
    const float* __restrict__ bias, unsigned short* __restrict__ C) {
  __shared__ unsigned short sA[128 * 64];
  __shared__ unsigned short sB[128 * 64];
  const int t = threadIdx.x;
  const int lane = t & 63, w = t >> 6;
  const int m0 = blockIdx.x << 7;
  const int n0 = blockIdx.y << 7;
  const int wr = (w >> 1) << 6, wc = (w & 1) << 6;
  const int srow = t >> 3, scol = (t & 7) << 3;
  const int l15 = lane & 15, lk = (lane >> 4) << 3;

  f32x4 acc[4][4];
  #pragma unroll
  for (int i = 0; i < 4; ++i)
    #pragma unroll
    for (int j = 0; j < 4; ++j) acc[i][j] = (f32x4){0.f, 0.f, 0.f, 0.f};

  for (int kt = 0; kt < 512; kt += 64) {
    __syncthreads();
    #pragma unroll
    for (int r = 0; r < 4; ++r) {
      const int row = (r << 5) + srow;
      async_copy16(A  + (size_t)(m0 + row) * 512 + kt + scol, sA + row * 64 + scol);
      async_copy16(Bt + (size_t)(n0 + row) * 512 + kt + scol, sB + row * 64 + scol);
    }
    __syncthreads();
    #pragma unroll
    for (int ks = 0; ks < 2; ++ks) {
      bf16x8 af[4], bfr[4];
      #pragma unroll
      for (int mf = 0; mf < 4; ++mf)
        af[mf] = *(const bf16x8*)(sA + (wr + mf * 16 + l15) * 64 + ks * 32 + lk);
      #pragma unroll
      for (int nf = 0; nf < 4; ++nf)
        bfr[nf] = *(const bf16x8*)(sB + (wc + nf * 16 + l15) * 64 + ks * 32 + lk);
      #pragma unroll
      for (int mf = 0; mf < 4; ++mf)
        #pragma unroll
        for (int nf = 0; nf < 4; ++nf)
          acc[mf][nf] = __builtin_amdgcn_mfma_f32_16x16x32_bf16(
              af[mf], bfr[nf], acc[mf][nf], 0, 0, 0);
    }
  }
  const int rbase = (lane >> 4) << 2;
  #pragma unroll
  for (int nf = 0; nf < 4; ++nf) {
    const int n = n0 + wc + nf * 16 + l15;
    const float bs = bias[n];
    #pragma unroll
    for (int mf = 0; mf < 4; ++mf) {
      #pragma unroll
      for (int q = 0; q < 4; ++q) {
        const int m = m0 + wr + mf * 16 + rbase + q;
        float v = acc[mf][nf][q] + bs;
        C[(size_t)m * 512 + n] = f2bf(fmaxf(v, 0.f));
      }
    }
  }
}

// ---------------- K3: GEMV + sigmoid + MSE partial --------------------------
__global__ __launch_bounds__(256) void final_loss(
    const unsigned short* __restrict__ h2, const float* __restrict__ w3,
    const float* __restrict__ b3, const float* __restrict__ rate,
    float* __restrict__ accs) {
  __shared__ float red[4];
  const int t = threadIdx.x, lane = t & 63, w = t >> 6;
  const int b = (blockIdx.x << 2) + w;
  const int d0 = lane << 3;
  ushort8 h = *(const ushort8*)(h2 + (size_t)b * D_SZ + d0);
  float4 w30 = *(const float4*)(w3 + d0), w31 = *(const float4*)(w3 + d0 + 4);
  float s = bf2f(h[0]) * w30.x + bf2f(h[1]) * w30.y + bf2f(h[2]) * w30.z +
            bf2f(h[3]) * w30.w + bf2f(h[4]) * w31.x + bf2f(h[5]) * w31.y +
            bf2f(h[6]) * w31.z + bf2f(h[7]) * w31.w;
  #pragma unroll
  for (int off = 32; off; off >>= 1) s += __shfl_down(s, off);
  if (lane == 0) {
    float logit = s + b3[0];
    float pred = 1.f + 4.f / (1.f + expf(-logit));
    float d = pred - rate[b];
    red[w] = d * d;
  }
  __syncthreads();
  if (t == 0) atomicAdd(&accs[0], red[0] + red[1] + red[2] + red[3]);
}

// ---------------- K4: combine ----------------------------------------------
__global__ void finalize(const float* __restrict__ accs, float* __restrict__ out) {
  out[0] = accs[0] * (1.f / (float)B_SZ) + accs[1] * (0.5e-4f / (float)B_SZ);
}

extern "C" void kernel_launch(void* const* d_in, const int* in_sizes, int n_in,
                              void* d_out, int out_size, void* d_ws, size_t ws_size,
                              hipStream_t stream) {
  const int* user = (const int*)d_in[0];
  const int* item = (const int*)d_in[1];
  const int* cate = (const int*)d_in[2];
  const float* rate = (const float*)d_in[3];
  const float* uw = (const float*)d_in[4];
  const float* iw = (const float*)d_in[5];
  const float* cw = (const float*)d_in[6];
  const float* prior = (const float*)d_in[7];
  const float* w1 = (const float*)d_in[8];
  const float* b1 = (const float*)d_in[9];
  const float* w2 = (const float*)d_in[10];
  const float* b2 = (const float*)d_in[11];
  const float* w3 = (const float*)d_in[12];
  const float* b3 = (const float*)d_in[13];
  float* out = (float*)d_out;

  unsigned short* fm  = (unsigned short*)d_ws;             // [B,512] bf16; reused as h2
  unsigned short* h1  = fm + (size_t)B_SZ * D_SZ;          // [B,512] bf16
  unsigned short* w1t = h1 + (size_t)B_SZ * D_SZ;          // [512,512] bf16 (transposed)
  unsigned short* w2t = w1t + 262144;
  float* k1 = (float*)(w2t + 262144);                      // [512]
  float* k2 = k1 + 512;                                    // [512]
  float* accs = k2 + 512;                                  // [2]: loss_sum, reg_sum

  hipMemsetAsync(accs, 0, 2 * sizeof(float), stream);
  prep_cs<<<8, 256, 0, stream>>>(cw, prior, k1, k2);
  wt_conv<<<2048, 256, 0, stream>>>(w1, w2, w1t, w2t);
  gather_fm<<<B_SZ / 4, 256, 0, stream>>>(user, item, cate, uw, iw, cw, k1, k2, fm, accs);
  gemm_relu<<<dim3(B_SZ / 128, 4), 256, 0, stream>>>(fm, w1t, b1, h1);
  gemm_relu<<<dim3(B_SZ / 128, 4), 256, 0, stream>>>(h1, w2t, b2, fm);
  final_loss<<<B_SZ / 4, 256, 0, stream>>>(fm, w3, b3, rate, accs);
  finalize<<<1, 1, 0, stream>>>(accs, out);
}

// Round 2
// 120.663 us; speedup vs baseline: 2.4383x; 2.4383x over previous
//
#include <hip/hip_runtime.h>
#include <hip/hip_bf16.h>
#include <math.h>

#define B_SZ 16384
#define D_SZ 512
#define C_SZ 2000

typedef __bf16 bf16x8 __attribute__((ext_vector_type(8)));
typedef float f32x4 __attribute__((ext_vector_type(4)));
typedef unsigned short ushort8 __attribute__((ext_vector_type(8)));

__device__ __forceinline__ unsigned short f2bf(float f) {
  unsigned int u = __builtin_bit_cast(unsigned int, f);
  u += 0x7fffu + ((u >> 16) & 1u);
  return (unsigned short)(u >> 16);
}
__device__ __forceinline__ float bf2f(unsigned short h) {
  unsigned int u = ((unsigned int)h) << 16;
  return __builtin_bit_cast(float, u);
}

#define GLOBAL_AS __attribute__((address_space(1)))
#define LDS_AS __attribute__((address_space(3)))
__device__ __forceinline__ void async_copy16(const void* g, void* l) {
  __builtin_amdgcn_global_load_lds((const GLOBAL_AS unsigned int*)g,
                                   (LDS_AS unsigned int*)l, 16, 0, 0);
}

// ---------------- K0: cs/css partial sums (128 blocks, atomic combine) ------
__global__ __launch_bounds__(256) void prep_cs(const float* __restrict__ cw,
                                               const float* __restrict__ prior,
                                               float* __restrict__ cs,
                                               float* __restrict__ css) {
  __shared__ float ls[2][4][64];
  const int t = threadIdx.x;
  const int dl = t & 63, g = t >> 6;
  const int dchunk = blockIdx.x & 7, cchunk = blockIdx.x >> 3;  // 8 x 16
  const int d = (dchunk << 6) + dl;
  const int cstart = cchunk * 125, cend = cstart + 125;
  float s = 0.f, ss = 0.f;
  for (int c = cstart + g; c < cend; c += 4) {
    float w = cw[(size_t)c * D_SZ + d] * prior[c];
    s += w; ss += w * w;
  }
  ls[0][g][dl] = s; ls[1][g][dl] = ss;
  __syncthreads();
  if (t < 64) {
    atomicAdd(cs + (dchunk << 6) + t,
              ls[0][0][t] + ls[0][1][t] + ls[0][2][t] + ls[0][3][t]);
    atomicAdd(css + (dchunk << 6) + t,
              ls[1][0][t] + ls[1][1][t] + ls[1][2][t] + ls[1][3][t]);
  }
}

// ---------------- K0b: w1,w2 -> transposed bf16 [N][K], LDS-tiled -----------
__global__ __launch_bounds__(256) void wt_conv(const float* __restrict__ w1,
                                               const float* __restrict__ w2,
                                               unsigned short* __restrict__ w1t,
                                               unsigned short* __restrict__ w2t) {
  __shared__ float tile[64][65];
  int bid = blockIdx.x;  // 0..127
  const float* src = w1; unsigned short* dst = w1t;
  if (bid >= 64) { src = w2; dst = w2t; bid -= 64; }
  const int kt = (bid >> 3) << 6;  // k-tile base
  const int nt = (bid & 7) << 6;   // n-tile base
  const int t = threadIdx.x;
  const int r0 = t >> 4, c0 = (t & 15) << 2;
  #pragma unroll
  for (int rr = 0; rr < 4; ++rr) {
    const int r = r0 + rr * 16;
    float4 v = *(const float4*)(src + (size_t)(kt + r) * 512 + nt + c0);
    tile[r][c0] = v.x; tile[r][c0 + 1] = v.y;
    tile[r][c0 + 2] = v.z; tile[r][c0 + 3] = v.w;
  }
  __syncthreads();
  const int nr = t >> 2, kc = (t & 3) << 4;
  ushort8 o0, o1;
  #pragma unroll
  for (int j = 0; j < 8; ++j) o0[j] = f2bf(tile[kc + j][nr]);
  #pragma unroll
  for (int j = 0; j < 8; ++j) o1[j] = f2bf(tile[kc + 8 + j][nr]);
  *(ushort8*)(dst + (size_t)(nt + nr) * 512 + kt + kc) = o0;
  *(ushort8*)(dst + (size_t)(nt + nr) * 512 + kt + kc + 8) = o1;
}

// ---------------- K1: gather + FM + reg partial -----------------------------
__device__ __forceinline__ float fme(float u, float i, float c, float s, float ssq,
                                     float& reg) {
  float ucm = fmaf(u, s, 0.5f * (s * s - ssq));
  float s2 = u + i + c + ucm;
  float q2 = u * u + i * i + c * c + ucm * ucm;
  reg += u * u + i * i + c * c;
  return 0.5f * (s2 * s2 - q2);
}

__global__ __launch_bounds__(256) void gather_fm(
    const int* __restrict__ user, const int* __restrict__ item,
    const int* __restrict__ cate,
    const float* __restrict__ uw, const float* __restrict__ iw,
    const float* __restrict__ cw,
    const float* __restrict__ cs, const float* __restrict__ css,
    unsigned short* __restrict__ fm, float* __restrict__ accs) {
  __shared__ float red[4];
  const int t = threadIdx.x, lane = t & 63, w = t >> 6;
  const int b = (blockIdx.x << 2) + w;
  const int d0 = lane << 3;
  const size_t uo = (size_t)user[b] * D_SZ + d0;
  const size_t io = (size_t)item[b] * D_SZ + d0;
  const size_t co = (size_t)cate[b] * D_SZ + d0;
  float4 u0 = *(const float4*)(uw + uo), u1 = *(const float4*)(uw + uo + 4);
  float4 i0 = *(const float4*)(iw + io), i1 = *(const float4*)(iw + io + 4);
  float4 c0 = *(const float4*)(cw + co), c1 = *(const float4*)(cw + co + 4);
  float4 s0 = *(const float4*)(cs + d0), s1 = *(const float4*)(cs + d0 + 4);
  float4 q0 = *(const float4*)(css + d0), q1 = *(const float4*)(css + d0 + 4);
  float regp = 0.f;
  ushort8 o;
  o[0] = f2bf(fme(u0.x, i0.x, c0.x, s0.x, q0.x, regp));
  o[1] = f2bf(fme(u0.y, i0.y, c0.y, s0.y, q0.y, regp));
  o[2] = f2bf(fme(u0.z, i0.z, c0.z, s0.z, q0.z, regp));
  o[3] = f2bf(fme(u0.w, i0.w, c0.w, s0.w, q0.w, regp));
  o[4] = f2bf(fme(u1.x, i1.x, c1.x, s1.x, q1.x, regp));
  o[5] = f2bf(fme(u1.y, i1.y, c1.y, s1.y, q1.y, regp));
  o[6] = f2bf(fme(u1.z, i1.z, c1.z, s1.z, q1.z, regp));
  o[7] = f2bf(fme(u1.w, i1.w, c1.w, s1.w, q1.w, regp));
  *(ushort8*)(fm + (size_t)b * D_SZ + d0) = o;
  #pragma unroll
  for (int off = 32; off; off >>= 1) regp += __shfl_down(regp, off);
  if (lane == 0) red[w] = regp;
  __syncthreads();
  if (t == 0) atomicAdd(&accs[1], red[0] + red[1] + red[2] + red[3]);
}

// ---------------- K2: bf16 GEMM + bias + relu -> bf16 C ---------------------
__global__ __launch_bounds__(256) void gemm_relu(
    const unsigned short* __restrict__ A, const unsigned short* __restrict__ Bt,
    const float* __restrict__ bias, unsigned short* __restrict__ C) {
  __shared__ unsigned short sA[128 * 64];
  __shared__ unsigned short sB[128 * 64];
  const int t = threadIdx.x;
  const int lane = t & 63, w = t >> 6;
  const int m0 = blockIdx.x << 7;
  const int n0 = blockIdx.y << 7;
  const int wr = (w >> 1) << 6, wc = (w & 1) << 6;
  const int srow = t >> 3, scol = (t & 7) << 3;
  const int l15 = lane & 15, lk = (lane >> 4) << 3;

  f32x4 acc[4][4];
  #pragma unroll
  for (int i = 0; i < 4; ++i)
    #pragma unroll
    for (int j = 0; j < 4; ++j) acc[i][j] = (f32x4){0.f, 0.f, 0.f, 0.f};

  for (int kt = 0; kt < 512; kt += 64) {
    __syncthreads();
    #pragma unroll
    for (int r = 0; r < 4; ++r) {
      const int row = (r << 5) + srow;
      async_copy16(A  + (size_t)(m0 + row) * 512 + kt + scol, sA + row * 64 + scol);
      async_copy16(Bt + (size_t)(n0 + row) * 512 + kt + scol, sB + row * 64 + scol);
    }
    __syncthreads();
    #pragma unroll
    for (int ks = 0; ks < 2; ++ks) {
      bf16x8 af[4], bfr[4];
      #pragma unroll
      for (int mf = 0; mf < 4; ++mf)
        af[mf] = *(const bf16x8*)(sA + (wr + mf * 16 + l15) * 64 + ks * 32 + lk);
      #pragma unroll
      for (int nf = 0; nf < 4; ++nf)
        bfr[nf] = *(const bf16x8*)(sB + (wc + nf * 16 + l15) * 64 + ks * 32 + lk);
      #pragma unroll
      for (int mf = 0; mf < 4; ++mf)
        #pragma unroll
        for (int nf = 0; nf < 4; ++nf)
          acc[mf][nf] = __builtin_amdgcn_mfma_f32_16x16x32_bf16(
              af[mf], bfr[nf], acc[mf][nf], 0, 0, 0);
    }
  }
  const int rbase = (lane >> 4) << 2;
  #pragma unroll
  for (int nf = 0; nf < 4; ++nf) {
    const int n = n0 + wc + nf * 16 + l15;
    const float bs = bias[n];
    #pragma unroll
    for (int mf = 0; mf < 4; ++mf) {
      #pragma unroll
      for (int q = 0; q < 4; ++q) {
        const int m = m0 + wr + mf * 16 + rbase + q;
        float v = acc[mf][nf][q] + bs;
        C[(size_t)m * 512 + n] = f2bf(fmaxf(v, 0.f));
      }
    }
  }
}

// ---------------- K2b: bf16 GEMM + bias + relu + w3 dot -> logits (atomic) --
__global__ __launch_bounds__(256) void gemm_dot(
    const unsigned short* __restrict__ A, const unsigned short* __restrict__ Bt,
    const float* __restrict__ bias, const float* __restrict__ w3,
    float* __restrict__ logits) {
  __shared__ unsigned short sA[128 * 64];
  __shared__ unsigned short sB[128 * 64];
  const int t = threadIdx.x;
  const int lane = t & 63, w = t >> 6;
  const int m0 = blockIdx.x << 7;
  const int n0 = blockIdx.y << 7;
  const int wr = (w >> 1) << 6, wc = (w & 1) << 6;
  const int srow = t >> 3, scol = (t & 7) << 3;
  const int l15 = lane & 15, lk = (lane >> 4) << 3;

  f32x4 acc[4][4];
  #pragma unroll
  for (int i = 0; i < 4; ++i)
    #pragma unroll
    for (int j = 0; j < 4; ++j) acc[i][j] = (f32x4){0.f, 0.f, 0.f, 0.f};

  for (int kt = 0; kt < 512; kt += 64) {
    __syncthreads();
    #pragma unroll
    for (int r = 0; r < 4; ++r) {
      const int row = (r << 5) + srow;
      async_copy16(A  + (size_t)(m0 + row) * 512 + kt + scol, sA + row * 64 + scol);
      async_copy16(Bt + (size_t)(n0 + row) * 512 + kt + scol, sB + row * 64 + scol);
    }
    __syncthreads();
    #pragma unroll
    for (int ks = 0; ks < 2; ++ks) {
      bf16x8 af[4], bfr[4];
      #pragma unroll
      for (int mf = 0; mf < 4; ++mf)
        af[mf] = *(const bf16x8*)(sA + (wr + mf * 16 + l15) * 64 + ks * 32 + lk);
      #pragma unroll
      for (int nf = 0; nf < 4; ++nf)
        bfr[nf] = *(const bf16x8*)(sB + (wc + nf * 16 + l15) * 64 + ks * 32 + lk);
      #pragma unroll
      for (int mf = 0; mf < 4; ++mf)
        #pragma unroll
        for (int nf = 0; nf < 4; ++nf)
          acc[mf][nf] = __builtin_amdgcn_mfma_f32_16x16x32_bf16(
              af[mf], bfr[nf], acc[mf][nf], 0, 0, 0);
    }
  }
  const int rbase = (lane >> 4) << 2;
  float bs[4], wv[4];
  #pragma unroll
  for (int nf = 0; nf < 4; ++nf) {
    const int n = n0 + wc + nf * 16 + l15;
    bs[nf] = bias[n];
    wv[nf] = w3[n];
  }
  #pragma unroll
  for (int mf = 0; mf < 4; ++mf) {
    #pragma unroll
    for (int q = 0; q < 4; ++q) {
      float v = 0.f;
      #pragma unroll
      for (int nf = 0; nf < 4; ++nf)
        v += fmaxf(acc[mf][nf][q] + bs[nf], 0.f) * wv[nf];
      v += __shfl_xor(v, 1);
      v += __shfl_xor(v, 2);
      v += __shfl_xor(v, 4);
      v += __shfl_xor(v, 8);
      if (l15 == 0) atomicAdd(logits + m0 + wr + mf * 16 + rbase + q, v);
    }
  }
}

// ---------------- K3: sigmoid + MSE partial ---------------------------------
__global__ __launch_bounds__(256) void rate_loss(
    const float* __restrict__ logits, const float* __restrict__ b3,
    const float* __restrict__ rate, float* __restrict__ accs) {
  __shared__ float red[4];
  const int t = threadIdx.x, lane = t & 63, w = t >> 6;
  const int i = blockIdx.x * 256 + t;
  float logit = logits[i] + b3[0];
  float pred = 1.f + 4.f / (1.f + expf(-logit));
  float d = pred - rate[i];
  float v = d * d;
  #pragma unroll
  for (int off = 32; off; off >>= 1) v += __shfl_down(v, off);
  if (lane == 0) red[w] = v;
  __syncthreads();
  if (t == 0) atomicAdd(&accs[0], red[0] + red[1] + red[2] + red[3]);
}

// ---------------- K4: combine ----------------------------------------------
__global__ void finalize(const float* __restrict__ accs, float* __restrict__ out) {
  out[0] = accs[0] * (1.f / (float)B_SZ) + accs[1] * (0.5e-4f / (float)B_SZ);
}

extern "C" void kernel_launch(void* const* d_in, const int* in_sizes, int n_in,
                              void* d_out, int out_size, void* d_ws, size_t ws_size,
                              hipStream_t stream) {
  const int* user = (const int*)d_in[0];
  const int* item = (const int*)d_in[1];
  const int* cate = (const int*)d_in[2];
  const float* rate = (const float*)d_in[3];
  const float* uw = (const float*)d_in[4];
  const float* iw = (const float*)d_in[5];
  const float* cw = (const float*)d_in[6];
  const float* prior = (const float*)d_in[7];
  const float* w1 = (const float*)d_in[8];
  const float* b1 = (const float*)d_in[9];
  const float* w2 = (const float*)d_in[10];
  const float* b2 = (const float*)d_in[11];
  const float* w3 = (const float*)d_in[12];
  const float* b3 = (const float*)d_in[13];
  float* out = (float*)d_out;

  unsigned short* fm  = (unsigned short*)d_ws;             // [B,512] bf16
  unsigned short* h1  = fm + (size_t)B_SZ * D_SZ;          // [B,512] bf16
  unsigned short* w1t = h1 + (size_t)B_SZ * D_SZ;          // [512,512] bf16 [N][K]
  unsigned short* w2t = w1t + 262144;
  float* cs     = (float*)(w2t + 262144);                  // [512]
  float* css    = cs + 512;                                // [512]
  float* logits = css + 512;                               // [16384]
  float* accs   = logits + B_SZ;                           // [2]: loss_sum, reg_sum

  // zero cs, css, logits, accs in one shot
  hipMemsetAsync(cs, 0, (512 + 512 + B_SZ + 2) * sizeof(float), stream);
  prep_cs<<<128, 256, 0, stream>>>(cw, prior, cs, css);
  wt_conv<<<128, 256, 0, stream>>>(w1, w2, w1t, w2t);
  gather_fm<<<B_SZ / 4, 256, 0, stream>>>(user, item, cate, uw, iw, cw, cs, css, fm, accs);
  gemm_relu<<<dim3(B_SZ / 128, 4), 256, 0, stream>>>(fm, w1t, b1, h1);
  gemm_dot<<<dim3(B_SZ / 128, 4), 256, 0, stream>>>(h1, w2t, b2, w3, logits);
  rate_loss<<<B_SZ / 256, 256, 0, stream>>>(logits, b3, rate, accs);
  finalize<<<1, 1, 0, stream>>>(accs, out);
}

// Round 5
// 113.193 us; speedup vs baseline: 2.5992x; 1.0660x over previous
//
#include <hip/hip_runtime.h>
#include <hip/hip_bf16.h>
#include <math.h>

#define B_SZ 16384
#define D_SZ 512
#define C_SZ 2000

typedef __bf16 bf16x8 __attribute__((ext_vector_type(8)));
typedef float f32x4 __attribute__((ext_vector_type(4)));
typedef unsigned short ushort8 __attribute__((ext_vector_type(8)));

__device__ __forceinline__ unsigned short f2bf(float f) {
  unsigned int u = __builtin_bit_cast(unsigned int, f);
  u += 0x7fffu + ((u >> 16) & 1u);
  return (unsigned short)(u >> 16);
}

// ---------------- K0a: cs/css partial sums (proven round-2 code) ------------
__global__ __launch_bounds__(256) void prep_cs(const float* __restrict__ cw,
                                               const float* __restrict__ prior,
                                               float* __restrict__ cs,
                                               float* __restrict__ css) {
  __shared__ float ls[2][4][64];
  const int t = threadIdx.x;
  const int dl = t & 63, g = t >> 6;
  const int dchunk = blockIdx.x & 7, cchunk = blockIdx.x >> 3;  // 8 x 16
  const int d = (dchunk << 6) + dl;
  const int cstart = cchunk * 125, cend = cstart + 125;
  float s = 0.f, ss = 0.f;
  for (int c = cstart + g; c < cend; c += 4) {
    float w = cw[(size_t)c * D_SZ + d] * prior[c];
    s += w; ss += w * w;
  }
  ls[0][g][dl] = s; ls[1][g][dl] = ss;
  __syncthreads();
  if (t < 64) {
    atomicAdd(cs + (dchunk << 6) + t,
              ls[0][0][t] + ls[0][1][t] + ls[0][2][t] + ls[0][3][t]);
    atomicAdd(css + (dchunk << 6) + t,
              ls[1][0][t] + ls[1][1][t] + ls[1][2][t] + ls[1][3][t]);
  }
}

// ---------------- K0b: w1,w2 -> bf16 [N][K] transpose (proven round-2 code) -
__global__ __launch_bounds__(256) void wt_conv(const float* __restrict__ w1,
                                               const float* __restrict__ w2,
                                               unsigned short* __restrict__ w1t,
                                               unsigned short* __restrict__ w2t) {
  __shared__ float tile[64][65];
  int bid = blockIdx.x;  // 0..127
  const float* src = w1; unsigned short* dst = w1t;
  if (bid >= 64) { src = w2; dst = w2t; bid -= 64; }
  const int kt = (bid >> 3) << 6;
  const int nt = (bid & 7) << 6;
  const int t = threadIdx.x;
  const int r0 = t >> 4, c0 = (t & 15) << 2;
  #pragma unroll
  for (int rr = 0; rr < 4; ++rr) {
    const int r = r0 + rr * 16;
    float4 v = *(const float4*)(src + (size_t)(kt + r) * 512 + nt + c0);
    tile[r][c0] = v.x; tile[r][c0 + 1] = v.y;
    tile[r][c0 + 2] = v.z; tile[r][c0 + 3] = v.w;
  }
  __syncthreads();
  const int nr = t >> 2, kc = (t & 3) << 4;
  ushort8 o0, o1;
  #pragma unroll
  for (int j = 0; j < 8; ++j) o0[j] = f2bf(tile[kc + j][nr]);
  #pragma unroll
  for (int j = 0; j < 8; ++j) o1[j] = f2bf(tile[kc + 8 + j][nr]);
  *(ushort8*)(dst + (size_t)(nt + nr) * 512 + kt + kc) = o0;
  *(ushort8*)(dst + (size_t)(nt + nr) * 512 + kt + kc + 8) = o1;
}

// ---------------- K1: mega — gather+FM -> gemm1 -> gemm2 -> dot -> loss ------
// 512 blocks x 256 threads; 32 rows/block; B read directly from global (L2).
__device__ __forceinline__ float fme(float u, float i, float c, float s, float ssq,
                                     float& reg) {
  float ucm = fmaf(u, s, 0.5f * (s * s - ssq));
  float s2 = u + i + c + ucm;
  float q2 = u * u + i * i + c * c + ucm * ucm;
  reg += u * u + i * i + c * c;
  return 0.5f * (s2 * s2 - q2);
}

__global__ __launch_bounds__(256) void mega(
    const int* __restrict__ user, const int* __restrict__ item,
    const int* __restrict__ cate, const float* __restrict__ rate,
    const float* __restrict__ uw, const float* __restrict__ iw,
    const float* __restrict__ cw, const float* __restrict__ cs,
    const float* __restrict__ css,
    const unsigned short* __restrict__ w1t, const unsigned short* __restrict__ w2t,
    const float* __restrict__ b1, const float* __restrict__ b2,
    const float* __restrict__ w3, const float* __restrict__ b3,
    float* __restrict__ accs) {
  __shared__ unsigned short sA[32 * 512];   // A-panel / h1, XOR-swizzled rows
  __shared__ float plog[4][33];
  __shared__ float red[4];
  const int t = threadIdx.x;
  const int lane = t & 63, w = t >> 6;
  const int r0 = blockIdx.x << 5;

  // ---- Phase A: gather + FM -> sA (swizzled bf16) ----
  {
    const int row = t >> 3;          // 0..31
    const int cb = (t & 7) << 6;     // col base (floats)
    const int b = r0 + row;
    const float* up = uw + (size_t)user[b] * D_SZ + cb;
    const float* ip = iw + (size_t)item[b] * D_SZ + cb;
    const float* cp = cw + (size_t)cate[b] * D_SZ + cb;
    const float* sp = cs + cb;
    const float* qp = css + cb;
    float regp = 0.f;
    const int aswz = (row & 7) << 3;
    #pragma unroll
    for (int j = 0; j < 8; ++j) {
      const int c8 = j << 3;
      float4 u0 = *(const float4*)(up + c8), u1 = *(const float4*)(up + c8 + 4);
      float4 i0 = *(const float4*)(ip + c8), i1 = *(const float4*)(ip + c8 + 4);
      float4 g0 = *(const float4*)(cp + c8), g1 = *(const float4*)(cp + c8 + 4);
      float4 s0 = *(const float4*)(sp + c8), s1 = *(const float4*)(sp + c8 + 4);
      float4 q0 = *(const float4*)(qp + c8), q1 = *(const float4*)(qp + c8 + 4);
      ushort8 o;
      o[0] = f2bf(fme(u0.x, i0.x, g0.x, s0.x, q0.x, regp));
      o[1] = f2bf(fme(u0.y, i0.y, g0.y, s0.y, q0.y, regp));
      o[2] = f2bf(fme(u0.z, i0.z, g0.z, s0.z, q0.z, regp));
      o[3] = f2bf(fme(u0.w, i0.w, g0.w, s0.w, q0.w, regp));
      o[4] = f2bf(fme(u1.x, i1.x, g1.x, s1.x, q1.x, regp));
      o[5] = f2bf(fme(u1.y, i1.y, g1.y, s1.y, q1.y, regp));
      o[6] = f2bf(fme(u1.z, i1.z, g1.z, s1.z, q1.z, regp));
      o[7] = f2bf(fme(u1.w, i1.w, g1.w, s1.w, q1.w, regp));
      *(ushort8*)(sA + (((row << 9) + cb + c8) ^ aswz)) = o;
    }
    #pragma unroll
    for (int off = 32; off; off >>= 1) regp += __shfl_down(regp, off);
    if (lane == 0) red[w] = regp;
  }
  __syncthreads();

  const int l15 = lane & 15;
  const int lk = (lane >> 4) << 3;        // k-offset within 32-run (shorts)
  const int swz = (l15 & 7) << 3;
  const int nw = w << 7;                  // wave's n-base (128 cols per wave)
  const int rbase = (lane >> 4) << 2;

  f32x4 acc[2][8];
  #pragma unroll
  for (int i = 0; i < 2; ++i)
    #pragma unroll
    for (int j = 0; j < 8; ++j) acc[i][j] = (f32x4){0.f, 0.f, 0.f, 0.f};

  // ---- Phase B: gemm1 (A = sA, B = w1t direct from global/L2) ----
  for (int kt = 0; kt < 512; kt += 64) {
    #pragma unroll
    for (int ks = 0; ks < 2; ++ks) {
      const int kk = kt + (ks << 5);
      const int k2x = kt + (((ks << 5) + lk) ^ swz);
      bf16x8 af[2], bb[8];
      #pragma unroll
      for (int mf = 0; mf < 2; ++mf)
        af[mf] = *(const bf16x8*)(sA + ((((mf << 4) + l15) << 9) + k2x));
      #pragma unroll
      for (int nf = 0; nf < 8; ++nf)
        bb[nf] = *(const bf16x8*)(w1t + ((size_t)(nw + (nf << 4) + l15) << 9) + kk + lk);
      #pragma unroll
      for (int mf = 0; mf < 2; ++mf)
        #pragma unroll
        for (int nf = 0; nf < 8; ++nf)
          acc[mf][nf] = __builtin_amdgcn_mfma_f32_16x16x32_bf16(
              af[mf], bb[nf], acc[mf][nf], 0, 0, 0);
    }
  }
  __syncthreads();

  // ---- h1 = relu(acc + b1) -> sA (bf16, swizzled) ----
  {
    #pragma unroll
    for (int nf = 0; nf < 8; ++nf) {
      const int col = nw + (nf << 4) + l15;
      const float b1c = b1[col];
      #pragma unroll
      for (int mf = 0; mf < 2; ++mf) {
        #pragma unroll
        for (int q = 0; q < 4; ++q) {
          const int row = (mf << 4) + rbase + q;
          float v = fmaxf(acc[mf][nf][q] + b1c, 0.f);
          sA[(row << 9) + (col ^ ((row & 7) << 3))] = f2bf(v);
        }
      }
    }
  }
  #pragma unroll
  for (int i = 0; i < 2; ++i)
    #pragma unroll
    for (int j = 0; j < 8; ++j) acc[i][j] = (f32x4){0.f, 0.f, 0.f, 0.f};
  __syncthreads();

  // ---- Phase C: gemm2 (A = h1 in sA, B = w2t direct) ----
  for (int kt = 0; kt < 512; kt += 64) {
    #pragma unroll
    for (int ks = 0; ks < 2; ++ks) {
      const int kk = kt + (ks << 5);
      const int k2x = kt + (((ks << 5) + lk) ^ swz);
      bf16x8 af[2], bb[8];
      #pragma unroll
      for (int mf = 0; mf < 2; ++mf)
        af[mf] = *(const bf16x8*)(sA + ((((mf << 4) + l15) << 9) + k2x));
      #pragma unroll
      for (int nf = 0; nf < 8; ++nf)
        bb[nf] = *(const bf16x8*)(w2t + ((size_t)(nw + (nf << 4) + l15) << 9) + kk + lk);
      #pragma unroll
      for (int mf = 0; mf < 2; ++mf)
        #pragma unroll
        for (int nf = 0; nf < 8; ++nf)
          acc[mf][nf] = __builtin_amdgcn_mfma_f32_16x16x32_bf16(
              af[mf], bb[nf], acc[mf][nf], 0, 0, 0);
    }
  }

  // ---- epilogue: relu + w3 dot -> per-wave logit partials ----
  {
    float b2c[8], wv[8];
    #pragma unroll
    for (int nf = 0; nf < 8; ++nf) {
      const int n = nw + (nf << 4) + l15;
      b2c[nf] = b2[n];
      wv[nf] = w3[n];
    }
    #pragma unroll
    for (int mf = 0; mf < 2; ++mf) {
      #pragma unroll
      for (int q = 0; q < 4; ++q) {
        float v = 0.f;
        #pragma unroll
        for (int nf = 0; nf < 8; ++nf)
          v += fmaxf(acc[mf][nf][q] + b2c[nf], 0.f) * wv[nf];
        v += __shfl_xor(v, 1);
        v += __shfl_xor(v, 2);
        v += __shfl_xor(v, 4);
        v += __shfl_xor(v, 8);
        if (l15 == 0) plog[w][(mf << 4) + rbase + q] = v;
      }
    }
  }
  __syncthreads();
  if (t < 32) {
    float s = plog[0][t] + plog[1][t] + plog[2][t] + plog[3][t];
    float logit = s + b3[0];
    float pred = 1.f + 4.f / (1.f + expf(-logit));
    float d = pred - rate[r0 + t];
    float v = d * d;
    #pragma unroll
    for (int off = 16; off; off >>= 1) v += __shfl_down(v, off);
    if (t == 0) atomicAdd(&accs[0], v);
  } else if (t == 32) {
    atomicAdd(&accs[1], red[0] + red[1] + red[2] + red[3]);
  }
}

// ---------------- K2: combine ----------------------------------------------
__global__ void finalize(const float* __restrict__ accs, float* __restrict__ out) {
  out[0] = accs[0] * (1.f / (float)B_SZ) + accs[1] * (0.5e-4f / (float)B_SZ);
}

extern "C" void kernel_launch(void* const* d_in, const int* in_sizes, int n_in,
                              void* d_out, int out_size, void* d_ws, size_t ws_size,
                              hipStream_t stream) {
  const int* user = (const int*)d_in[0];
  const int* item = (const int*)d_in[1];
  const int* cate = (const int*)d_in[2];
  const float* rate = (const float*)d_in[3];
  const float* uw = (const float*)d_in[4];
  const float* iw = (const float*)d_in[5];
  const float* cw = (const float*)d_in[6];
  const float* prior = (const float*)d_in[7];
  const float* w1 = (const float*)d_in[8];
  const float* b1 = (const float*)d_in[9];
  const float* w2 = (const float*)d_in[10];
  const float* b2 = (const float*)d_in[11];
  const float* w3 = (const float*)d_in[12];
  const float* b3 = (const float*)d_in[13];
  float* out = (float*)d_out;

  unsigned short* w1t = (unsigned short*)d_ws;   // [512*512] bf16 [N][K]
  unsigned short* w2t = w1t + 262144;
  float* cs   = (float*)(w2t + 262144);
  float* css  = cs + 512;
  float* accs = css + 512;                       // [2]

  hipMemsetAsync(cs, 0, (512 + 512 + 2) * sizeof(float), stream);
  prep_cs<<<128, 256, 0, stream>>>(cw, prior, cs, css);
  wt_conv<<<128, 256, 0, stream>>>(w1, w2, w1t, w2t);
  mega<<<512, 256, 0, stream>>>(user, item, cate, rate, uw, iw, cw, cs, css,
                                w1t, w2t, b1, b2, w3, b3, accs);
  finalize<<<1, 1, 0, stream>>>(accs, out);
}

// Round 6
// 106.061 us; speedup vs baseline: 2.7740x; 1.0672x over previous
//
#include <hip/hip_runtime.h>
#include <hip/hip_bf16.h>
#include <math.h>

#define B_SZ 16384
#define D_SZ 512
#define C_SZ 2000

typedef __bf16 bf16x8 __attribute__((ext_vector_type(8)));
typedef float f32x4 __attribute__((ext_vector_type(4)));
typedef unsigned short ushort8 __attribute__((ext_vector_type(8)));

__device__ __forceinline__ unsigned short f2bf(float f) {
  unsigned int u = __builtin_bit_cast(unsigned int, f);
  u += 0x7fffu + ((u >> 16) & 1u);
  return (unsigned short)(u >> 16);
}

// ---------------- K0: fused prep (cs/css partials + weight transpose) -------
// blocks 0..127  : cs/css partial sums (atomicAdd into zeroed cs/css)
// blocks 128..255: w1,w2 -> bf16 [N][K] transpose (64x64 tiles)
__global__ __launch_bounds__(256) void prep(
    const float* __restrict__ cw, const float* __restrict__ prior,
    const float* __restrict__ w1, const float* __restrict__ w2,
    float* __restrict__ cs, float* __restrict__ css,
    unsigned short* __restrict__ w1t, unsigned short* __restrict__ w2t) {
  __shared__ float ls[2][4][64];
  __shared__ float tile[64][65];
  const int t = threadIdx.x;
  int bid = blockIdx.x;
  if (bid < 128) {
    const int dl = t & 63, g = t >> 6;
    const int dchunk = bid & 7, cchunk = bid >> 3;  // 8 x 16
    const int d = (dchunk << 6) + dl;
    const int cstart = cchunk * 125, cend = cstart + 125;
    float s = 0.f, ss = 0.f;
    for (int c = cstart + g; c < cend; c += 4) {
      float w = cw[(size_t)c * D_SZ + d] * prior[c];
      s += w; ss += w * w;
    }
    ls[0][g][dl] = s; ls[1][g][dl] = ss;
    __syncthreads();
    if (t < 64) {
      atomicAdd(cs + (dchunk << 6) + t,
                ls[0][0][t] + ls[0][1][t] + ls[0][2][t] + ls[0][3][t]);
      atomicAdd(css + (dchunk << 6) + t,
                ls[1][0][t] + ls[1][1][t] + ls[1][2][t] + ls[1][3][t]);
    }
    return;
  }
  bid -= 128;
  const float* src = w1; unsigned short* dst = w1t;
  if (bid >= 64) { src = w2; dst = w2t; bid -= 64; }
  const int kt = (bid >> 3) << 6;
  const int nt = (bid & 7) << 6;
  const int r0 = t >> 4, c0 = (t & 15) << 2;
  #pragma unroll
  for (int rr = 0; rr < 4; ++rr) {
    const int r = r0 + rr * 16;
    float4 v = *(const float4*)(src + (size_t)(kt + r) * 512 + nt + c0);
    tile[r][c0] = v.x; tile[r][c0 + 1] = v.y;
    tile[r][c0 + 2] = v.z; tile[r][c0 + 3] = v.w;
  }
  __syncthreads();
  const int nr = t >> 2, kc = (t & 3) << 4;
  ushort8 o0, o1;
  #pragma unroll
  for (int j = 0; j < 8; ++j) o0[j] = f2bf(tile[kc + j][nr]);
  #pragma unroll
  for (int j = 0; j < 8; ++j) o1[j] = f2bf(tile[kc + 8 + j][nr]);
  *(ushort8*)(dst + (size_t)(nt + nr) * 512 + kt + kc) = o0;
  *(ushort8*)(dst + (size_t)(nt + nr) * 512 + kt + kc + 8) = o1;
}

// ---------------- K1: mega — gather+FM -> gemm1 -> gemm2 -> dot -> loss ------
__device__ __forceinline__ float fme(float u, float i, float c, float s, float ssq,
                                     float& reg) {
  float ucm = fmaf(u, s, 0.5f * (s * s - ssq));
  float s2 = u + i + c + ucm;
  float q2 = u * u + i * i + c * c + ucm * ucm;
  reg += u * u + i * i + c * c;
  return 0.5f * (s2 * s2 - q2);
}

__global__ __launch_bounds__(256) void mega(
    const int* __restrict__ user, const int* __restrict__ item,
    const int* __restrict__ cate, const float* __restrict__ rate,
    const float* __restrict__ uw, const float* __restrict__ iw,
    const float* __restrict__ cw, const float* __restrict__ cs,
    const float* __restrict__ css,
    const unsigned short* __restrict__ w1t, const unsigned short* __restrict__ w2t,
    const float* __restrict__ b1, const float* __restrict__ b2,
    const float* __restrict__ w3, const float* __restrict__ b3,
    float* __restrict__ accs, float* __restrict__ out) {
  __shared__ unsigned short sA[32 * 512];   // A-panel / h1, XOR-swizzled rows
  __shared__ float plog[4][33];
  __shared__ float red[4];
  const int t = threadIdx.x;
  const int lane = t & 63, w = t >> 6;
  const int r0 = blockIdx.x << 5;

  // ---- Phase A: gather + FM -> sA (swizzled bf16), fully coalesced ----
  // thread t covers row = t>>3; per j-iter the row's 8 threads read a
  // CONTIGUOUS 256B block (col = j*64 + (t&7)*8) -> full-line consumption,
  // no L1-retention dependence.
  {
    const int row = t >> 3;          // 0..31
    const int g8 = (t & 7) << 3;     // 0..56
    const int b = r0 + row;
    const float* up = uw + (size_t)user[b] * D_SZ;
    const float* ip = iw + (size_t)item[b] * D_SZ;
    const float* cp = cw + (size_t)cate[b] * D_SZ;
    float regp = 0.f;
    const int aswz = (row & 7) << 3;
    #pragma unroll
    for (int j = 0; j < 8; ++j) {
      const int col = (j << 6) + g8;
      float4 u0 = *(const float4*)(up + col), u1 = *(const float4*)(up + col + 4);
      float4 i0 = *(const float4*)(ip + col), i1 = *(const float4*)(ip + col + 4);
      float4 g0 = *(const float4*)(cp + col), g1 = *(const float4*)(cp + col + 4);
      float4 s0 = *(const float4*)(cs + col), s1 = *(const float4*)(cs + col + 4);
      float4 q0 = *(const float4*)(css + col), q1 = *(const float4*)(css + col + 4);
      ushort8 o;
      o[0] = f2bf(fme(u0.x, i0.x, g0.x, s0.x, q0.x, regp));
      o[1] = f2bf(fme(u0.y, i0.y, g0.y, s0.y, q0.y, regp));
      o[2] = f2bf(fme(u0.z, i0.z, g0.z, s0.z, q0.z, regp));
      o[3] = f2bf(fme(u0.w, i0.w, g0.w, s0.w, q0.w, regp));
      o[4] = f2bf(fme(u1.x, i1.x, g1.x, s1.x, q1.x, regp));
      o[5] = f2bf(fme(u1.y, i1.y, g1.y, s1.y, q1.y, regp));
      o[6] = f2bf(fme(u1.z, i1.z, g1.z, s1.z, q1.z, regp));
      o[7] = f2bf(fme(u1.w, i1.w, g1.w, s1.w, q1.w, regp));
      *(ushort8*)(sA + (((row << 9) + col) ^ aswz)) = o;
    }
    #pragma unroll
    for (int off = 32; off; off >>= 1) regp += __shfl_down(regp, off);
    if (lane == 0) red[w] = regp;
  }
  __syncthreads();

  const int l15 = lane & 15;
  const int lk = (lane >> 4) << 3;        // k-offset within 32-run (shorts)
  const int swz = (l15 & 7) << 3;
  const int nw = w << 7;                  // wave's n-base (128 cols per wave)
  const int rbase = (lane >> 4) << 2;

  f32x4 acc[2][8];
  #pragma unroll
  for (int i = 0; i < 2; ++i)
    #pragma unroll
    for (int j = 0; j < 8; ++j) acc[i][j] = (f32x4){0.f, 0.f, 0.f, 0.f};

  // ---- Phase B: gemm1 (A = sA, B = w1t direct from global/L2) ----
  for (int kt = 0; kt < 512; kt += 64) {
    #pragma unroll
    for (int ks = 0; ks < 2; ++ks) {
      const int kk = kt + (ks << 5);
      const int k2x = kt + (((ks << 5) + lk) ^ swz);
      bf16x8 af[2], bb[8];
      #pragma unroll
      for (int mf = 0; mf < 2; ++mf)
        af[mf] = *(const bf16x8*)(sA + ((((mf << 4) + l15) << 9) + k2x));
      #pragma unroll
      for (int nf = 0; nf < 8; ++nf)
        bb[nf] = *(const bf16x8*)(w1t + ((size_t)(nw + (nf << 4) + l15) << 9) + kk + lk);
      #pragma unroll
      for (int mf = 0; mf < 2; ++mf)
        #pragma unroll
        for (int nf = 0; nf < 8; ++nf)
          acc[mf][nf] = __builtin_amdgcn_mfma_f32_16x16x32_bf16(
              af[mf], bb[nf], acc[mf][nf], 0, 0, 0);
    }
  }
  __syncthreads();

  // ---- h1 = relu(acc + b1) -> sA (bf16, swizzled) ----
  {
    #pragma unroll
    for (int nf = 0; nf < 8; ++nf) {
      const int col = nw + (nf << 4) + l15;
      const float b1c = b1[col];
      #pragma unroll
      for (int mf = 0; mf < 2; ++mf) {
        #pragma unroll
        for (int q = 0; q < 4; ++q) {
          const int row = (mf << 4) + rbase + q;
          float v = fmaxf(acc[mf][nf][q] + b1c, 0.f);
          sA[(row << 9) + (col ^ ((row & 7) << 3))] = f2bf(v);
        }
      }
    }
  }
  #pragma unroll
  for (int i = 0; i < 2; ++i)
    #pragma unroll
    for (int j = 0; j < 8; ++j) acc[i][j] = (f32x4){0.f, 0.f, 0.f, 0.f};
  __syncthreads();

  // ---- Phase C: gemm2 (A = h1 in sA, B = w2t direct) ----
  for (int kt = 0; kt < 512; kt += 64) {
    #pragma unroll
    for (int ks = 0; ks < 2; ++ks) {
      const int kk = kt + (ks << 5);
      const int k2x = kt + (((ks << 5) + lk) ^ swz);
      bf16x8 af[2], bb[8];
      #pragma unroll
      for (int mf = 0; mf < 2; ++mf)
        af[mf] = *(const bf16x8*)(sA + ((((mf << 4) + l15) << 9) + k2x));
      #pragma unroll
      for (int nf = 0; nf < 8; ++nf)
        bb[nf] = *(const bf16x8*)(w2t + ((size_t)(nw + (nf << 4) + l15) << 9) + kk + lk);
      #pragma unroll
      for (int mf = 0; mf < 2; ++mf)
        #pragma unroll
        for (int nf = 0; nf < 8; ++nf)
          acc[mf][nf] = __builtin_amdgcn_mfma_f32_16x16x32_bf16(
              af[mf], bb[nf], acc[mf][nf], 0, 0, 0);
    }
  }

  // ---- epilogue: relu + w3 dot -> per-wave logit partials ----
  {
    float b2c[8], wv[8];
    #pragma unroll
    for (int nf = 0; nf < 8; ++nf) {
      const int n = nw + (nf << 4) + l15;
      b2c[nf] = b2[n];
      wv[nf] = w3[n];
    }
    #pragma unroll
    for (int mf = 0; mf < 2; ++mf) {
      #pragma unroll
      for (int q = 0; q < 4; ++q) {
        float v = 0.f;
        #pragma unroll
        for (int nf = 0; nf < 8; ++nf)
          v += fmaxf(acc[mf][nf][q] + b2c[nf], 0.f) * wv[nf];
        v += __shfl_xor(v, 1);
        v += __shfl_xor(v, 2);
        v += __shfl_xor(v, 4);
        v += __shfl_xor(v, 8);
        if (l15 == 0) plog[w][(mf << 4) + rbase + q] = v;
      }
    }
  }
  __syncthreads();
  if (t < 32) {
    float s = plog[0][t] + plog[1][t] + plog[2][t] + plog[3][t];
    float logit = s + b3[0];
    float pred = 1.f + 4.f / (1.f + expf(-logit));
    float d = pred - rate[r0 + t];
    float v = d * d;
    #pragma unroll
    for (int off = 16; off; off >>= 1) v += __shfl_down(v, off);
    if (t == 0) atomicAdd(&accs[0], v);
  } else if (t == 32) {
    atomicAdd(&accs[1], red[0] + red[1] + red[2] + red[3]);
  }
  // ---- fused finalize: last block combines ----
  __syncthreads();
  if (t == 0) {
    __threadfence();
    unsigned int prev = atomicAdd((unsigned int*)(accs + 2), 1u);
    if (prev == 511u) {
      __threadfence();
      float l = atomicAdd(&accs[0], 0.f);
      float r = atomicAdd(&accs[1], 0.f);
      out[0] = l * (1.f / (float)B_SZ) + r * (0.5e-4f / (float)B_SZ);
    }
  }
}

extern "C" void kernel_launch(void* const* d_in, const int* in_sizes, int n_in,
                              void* d_out, int out_size, void* d_ws, size_t ws_size,
                              hipStream_t stream) {
  const int* user = (const int*)d_in[0];
  const int* item = (const int*)d_in[1];
  const int* cate = (const int*)d_in[2];
  const float* rate = (const float*)d_in[3];
  const float* uw = (const float*)d_in[4];
  const float* iw = (const float*)d_in[5];
  const float* cw = (const float*)d_in[6];
  const float* prior = (const float*)d_in[7];
  const float* w1 = (const float*)d_in[8];
  const float* b1 = (const float*)d_in[9];
  const float* w2 = (const float*)d_in[10];
  const float* b2 = (const float*)d_in[11];
  const float* w3 = (const float*)d_in[12];
  const float* b3 = (const float*)d_in[13];
  float* out = (float*)d_out;

  unsigned short* w1t = (unsigned short*)d_ws;   // [512*512] bf16 [N][K]
  unsigned short* w2t = w1t + 262144;
  float* cs   = (float*)(w2t + 262144);
  float* css  = cs + 512;
  float* accs = css + 512;                       // [4]: loss, reg, counter, pad

  hipMemsetAsync(cs, 0, (512 + 512 + 4) * sizeof(float), stream);
  prep<<<256, 256, 0, stream>>>(cw, prior, w1, w2, cs, css, w1t, w2t);
  mega<<<512, 256, 0, stream>>>(user, item, cate, rate, uw, iw, cw, cs, css,
                                w1t, w2t, b1, b2, w3, b3, accs, out);
}